// Round 1
// baseline (229.409 us; speedup 1.0000x reference)
//
#include <hip/hip_runtime.h>

// CARAFE: x(8,256,64,64) -> comp(1x1 conv, 64ch, NHWC) -> enc(3x3 conv, 100ch)
// -> pixel_shuffle(2) -> softmax(25) -> reassembly -> out(8,256,128,128)
// K=5, G=1, S=2.

#define NB 8
#define CI 256
#define HH 64
#define WW 64
#define KC 64     // compressed channels
#define KK 25     // kernel positions (5x5)

// ---------------- kernel 0: weight re-layout ----------------
// wT1[c][o]  (256x64)           = w_comp[o*256 + c]
// wT2[sp][tap][c][j(pad32)]     = w_enc[(j*4+sp)*576 + c*9 + tap]   (j<25, else 0)
__global__ __launch_bounds__(256) void prep_weights(const float* __restrict__ w_comp,
                                                    const float* __restrict__ w_enc,
                                                    float* __restrict__ wT1,
                                                    float* __restrict__ wT2) {
    int i = blockIdx.x * 256 + threadIdx.x;
    if (i < 256 * 64) {
        int c = i >> 6, o = i & 63;
        wT1[i] = w_comp[o * 256 + c];
    }
    if (i < 4 * 9 * 64 * 32) {
        int j   = i & 31;
        int c   = (i >> 5) & 63;
        int sptap = i >> 11;          // sp*9 + tap
        int tap = sptap % 9;
        int sp  = i / (9 * 64 * 32);
        float v = 0.f;
        if (j < 25) v = w_enc[(j * 4 + sp) * 576 + c * 9 + tap];
        wT2[i] = v;
    }
}

// ---------------- kernel 1: 1x1 conv (256 -> 64), comp stored NHWC ----------------
// block: 256 threads = (64 w, 4 og), each thread computes 16 outputs for one pixel.
// grid: n*h = 512 blocks.
__global__ __launch_bounds__(256) void conv1x1(const float* __restrict__ x,
                                               const float* __restrict__ wT1,
                                               const float* __restrict__ b_comp,
                                               float* __restrict__ comp) {
    int w  = threadIdx.x & 63;
    int og = __builtin_amdgcn_readfirstlane(threadIdx.x >> 6);  // 0..3, wave-uniform
    int h  = blockIdx.x & 63;
    int n  = blockIdx.x >> 6;

    const float* xp = x + ((size_t)n * CI) * 4096 + h * 64 + w;
    const float* wp = wT1 + og * 16;

    float acc[16];
#pragma unroll
    for (int k = 0; k < 16; k++) acc[k] = 0.f;

    for (int c = 0; c < CI; c++) {
        float v = xp[(size_t)c * 4096];
#pragma unroll
        for (int k = 0; k < 16; k++) acc[k] += wp[c * 64 + k] * v;
    }

    float* cp = comp + ((size_t)(blockIdx.x * 64 + w)) * 64 + og * 16;
    float4* cp4 = reinterpret_cast<float4*>(cp);
#pragma unroll
    for (int q = 0; q < 4; q++) {
        cp4[q] = make_float4(acc[4 * q + 0] + b_comp[og * 16 + 4 * q + 0],
                             acc[4 * q + 1] + b_comp[og * 16 + 4 * q + 1],
                             acc[4 * q + 2] + b_comp[og * 16 + 4 * q + 2],
                             acc[4 * q + 3] + b_comp[og * 16 + 4 * q + 3]);
    }
}

// ---------------- kernel 2: 3x3 conv (64 -> 100) + pixel-shuffle + softmax ----------------
// Each wave owns one subpixel class sp = r1*2+r2; its 25 outputs o = 4j+sp form
// exactly one softmax group -> softmax is thread-local.
// block: 256 = (64 w, 4 sp). grid: n*h = 512 blocks.
// mask layout: [pixel][sp][25]  (100 floats / source pixel, contiguous)
__global__ __launch_bounds__(256) void conv3x3_softmax(const float* __restrict__ comp,
                                                       const float* __restrict__ wT2,
                                                       const float* __restrict__ b_enc,
                                                       float* __restrict__ mask) {
    int w  = threadIdx.x & 63;
    int sp = __builtin_amdgcn_readfirstlane(threadIdx.x >> 6);  // 0..3
    int h  = blockIdx.x & 63;
    int n  = blockIdx.x >> 6;

    float acc[25];
#pragma unroll
    for (int j = 0; j < 25; j++) acc[j] = b_enc[j * 4 + sp];

    const float* wbase = wT2 + sp * 9 * 64 * 32;

    for (int tap = 0; tap < 9; tap++) {
        int dy = tap / 3 - 1, dx = tap % 3 - 1;
        int y = h + dy;
        int xx = w + dx;
        int yc = min(max(y, 0), 63);
        int xc = min(max(xx, 0), 63);
        float vm = (y == yc && xx == xc) ? 1.f : 0.f;
        const float4* cp4 = reinterpret_cast<const float4*>(
            comp + ((size_t)((n * 64 + yc) * 64 + xc)) * 64);
        const float* wt = wbase + tap * 64 * 32;
        for (int c4 = 0; c4 < 16; c4++) {
            float4 v4 = cp4[c4];
            float v0 = v4.x * vm, v1 = v4.y * vm, v2 = v4.z * vm, v3 = v4.w * vm;
            const float* w0 = wt + (c4 * 4 + 0) * 32;
            const float* w1 = wt + (c4 * 4 + 1) * 32;
            const float* w2 = wt + (c4 * 4 + 2) * 32;
            const float* w3 = wt + (c4 * 4 + 3) * 32;
#pragma unroll
            for (int j = 0; j < 25; j++) {
                acc[j] += w0[j] * v0;
                acc[j] += w1[j] * v1;
                acc[j] += w2[j] * v2;
                acc[j] += w3[j] * v3;
            }
        }
    }

    // softmax over the 25 values (thread-local)
    float m = acc[0];
#pragma unroll
    for (int j = 1; j < 25; j++) m = fmaxf(m, acc[j]);
    float s = 0.f;
#pragma unroll
    for (int j = 0; j < 25; j++) { acc[j] = __expf(acc[j] - m); s += acc[j]; }
    float inv = 1.f / s;

    int pixel = blockIdx.x * 64 + w;
    float* mp = mask + (size_t)pixel * 100 + sp * 25;
#pragma unroll
    for (int j = 0; j < 25; j++) mp[j] = acc[j] * inv;
}

// ---------------- kernel 4: reassembly ----------------
// out[n,c,2h+r1,2w+r2] = sum_j mask[pixel][sp][j] * x[n,c,h+j/5-2,w+j%5-2]
// block: 256 = (64 w, 4 cq). thread handles 8 channels; grid: n*h*cgb = 8*64*8 = 4096.
__global__ __launch_bounds__(256) void reassemble(const float* __restrict__ x,
                                                  const float* __restrict__ mask,
                                                  float* __restrict__ out) {
    int w  = threadIdx.x & 63;
    int cq = threadIdx.x >> 6;   // 0..3
    int b  = blockIdx.x;
    int h  = b & 63;
    int rest = b >> 6;           // n*8 + cgb
    int cgb = rest & 7;
    int n   = rest >> 3;
    int c0  = cgb * 32 + cq * 8;

    int pixel = (n * 64 + h) * 64 + w;
    const float* mp = mask + (size_t)pixel * 100;

    float msk[100];
#pragma unroll
    for (int i = 0; i < 25; i++) {
        float4 v = reinterpret_cast<const float4*>(mp)[i];
        msk[i * 4 + 0] = v.x;
        msk[i * 4 + 1] = v.y;
        msk[i * 4 + 2] = v.z;
        msk[i * 4 + 3] = v.w;
    }

    // precompute clamped offsets + validity masks for the 5x5 window
    int yy0[5], xx0[5];
    float vmy[5], vmx[5];
#pragma unroll
    for (int d = 0; d < 5; d++) {
        int y = h + d - 2;
        int xcol = w + d - 2;
        int ycl = min(max(y, 0), 63);
        int xcl = min(max(xcol, 0), 63);
        yy0[d] = ycl * 64;
        xx0[d] = xcl;
        vmy[d] = (y == ycl) ? 1.f : 0.f;
        vmx[d] = (xcol == xcl) ? 1.f : 0.f;
    }

    for (int c = c0; c < c0 + 8; c++) {
        const float* xc = x + ((size_t)(n * CI + c)) * 4096;
        float xv[25];
#pragma unroll
        for (int j = 0; j < 25; j++) {
            int dy = j / 5, dx = j % 5;
            xv[j] = xc[yy0[dy] + xx0[dx]] * (vmy[dy] * vmx[dx]);
        }
        float a0 = 0.f, a1 = 0.f, a2 = 0.f, a3 = 0.f;
#pragma unroll
        for (int j = 0; j < 25; j++) {
            a0 += msk[0 * 25 + j] * xv[j];
            a1 += msk[1 * 25 + j] * xv[j];
            a2 += msk[2 * 25 + j] * xv[j];
            a3 += msk[3 * 25 + j] * xv[j];
        }
        float* op = out + ((size_t)(n * CI + c) * 128 + 2 * h) * 128 + 2 * w;
        reinterpret_cast<float2*>(op)[0] = make_float2(a0, a1);
        reinterpret_cast<float2*>(op + 128)[0] = make_float2(a2, a3);
    }
}

extern "C" void kernel_launch(void* const* d_in, const int* in_sizes, int n_in,
                              void* d_out, int out_size, void* d_ws, size_t ws_size,
                              hipStream_t stream) {
    const float* x      = (const float*)d_in[0];
    const float* w_comp = (const float*)d_in[1];
    const float* b_comp = (const float*)d_in[2];
    const float* w_enc  = (const float*)d_in[3];
    const float* b_enc  = (const float*)d_in[4];
    float* out = (float*)d_out;

    // workspace layout (floats)
    float* wT1  = (float*)d_ws;                    // 256*64        = 16384
    float* wT2  = wT1 + 16384;                     // 4*9*64*32     = 73728
    float* comp = wT2 + 73728;                     // 8*64*64*64    = 2097152 (NHWC)
    float* mask = comp + 2097152;                  // 32768*100     = 3276800
    // total ~21.9 MB

    prep_weights<<<288, 256, 0, stream>>>(w_comp, w_enc, wT1, wT2);
    conv1x1<<<512, 256, 0, stream>>>(x, wT1, b_comp, comp);
    conv3x3_softmax<<<512, 256, 0, stream>>>(comp, wT2, b_enc, mask);
    reassemble<<<4096, 256, 0, stream>>>(x, mask, out);
}

// Round 2
// 152.441 us; speedup vs baseline: 1.5049x; 1.5049x over previous
//
#include <hip/hip_runtime.h>

// CARAFE: x(8,256,64,64) fp32
//   -> conv1x1 (256->64) -> comp bf16 NHWC [32768][64]
//   -> conv3x3 (64->100) as bf16 MFMA GEMM (M=32768, N=112pad, K=576) + fused softmax
//   -> reassembly -> out(8,256,128,128) fp32
// K=5, G=1, S=2.

#define CI 256

typedef __attribute__((ext_vector_type(8))) short bf16x8;
typedef __attribute__((ext_vector_type(4))) float f32x4;

__device__ inline unsigned short f2bf(float f) {
    unsigned u = __float_as_uint(f);
    unsigned r = (u + 0x7FFF + ((u >> 16) & 1)) >> 16;
    return (unsigned short)r;
}

// ---------------- kernel 0: weight prep ----------------
// wT1[c][o] (256x64)          = w_comp[o*256 + c]                  (fp32)
// Bp[g][n][j] bf16 (g=k>>3)   : k=g*8+j, tap=k>>6, c=k&63, n<100 -> w_enc[n*576+c*9+tap]
// zp: 256B zero page for boundary taps
__global__ __launch_bounds__(256) void prep_weights(const float* __restrict__ w_comp,
                                                    const float* __restrict__ w_enc,
                                                    float* __restrict__ wT1,
                                                    unsigned short* __restrict__ Bp,
                                                    float* __restrict__ zp) {
    int i = blockIdx.x * 256 + threadIdx.x;
    if (i < 64) zp[i] = 0.f;
    if (i < 256 * 64) {
        int c = i >> 6, o = i & 63;
        wT1[i] = w_comp[o * 256 + c];
    }
    if (i < 72 * 112 * 8) {
        int j = i & 7;
        int n = (i >> 3) % 112;
        int g = i / (112 * 8);
        int k = g * 8 + j;
        int tap = k >> 6;
        int c = k & 63;
        float v = (n < 100) ? w_enc[n * 576 + c * 9 + tap] : 0.f;
        Bp[i] = f2bf(v);
    }
}

// ---------------- kernel 1: 1x1 conv (256 -> 64), comp stored bf16 NHWC ----------------
__global__ __launch_bounds__(256) void conv1x1(const float* __restrict__ x,
                                               const float* __restrict__ wT1,
                                               const float* __restrict__ b_comp,
                                               unsigned short* __restrict__ comp) {
    int w  = threadIdx.x & 63;
    int og = __builtin_amdgcn_readfirstlane(threadIdx.x >> 6);  // 0..3, wave-uniform
    const float* xp = x + ((size_t)(blockIdx.x >> 6) * CI) * 4096 + (blockIdx.x & 63) * 64 + w;
    const float* wp = wT1 + og * 16;

    float acc[16];
#pragma unroll
    for (int k = 0; k < 16; k++) acc[k] = 0.f;

    for (int c = 0; c < CI; c++) {
        float v = xp[(size_t)c * 4096];
#pragma unroll
        for (int k = 0; k < 16; k++) acc[k] += wp[c * 64 + k] * v;
    }

    unsigned short* cp = comp + ((size_t)(blockIdx.x * 64 + w)) * 64 + og * 16;
    unsigned vals[8];
#pragma unroll
    for (int q = 0; q < 8; q++) {
        unsigned lo = f2bf(acc[2 * q]     + b_comp[og * 16 + 2 * q]);
        unsigned hi = f2bf(acc[2 * q + 1] + b_comp[og * 16 + 2 * q + 1]);
        vals[q] = lo | (hi << 16);
    }
    reinterpret_cast<uint4*>(cp)[0] = uint4{vals[0], vals[1], vals[2], vals[3]};
    reinterpret_cast<uint4*>(cp)[1] = uint4{vals[4], vals[5], vals[6], vals[7]};
}

// ---------------- kernel 2: 3x3 conv as bf16 MFMA GEMM + fused softmax ----------------
// 1 wave/block. Wave: 32 pixels (2 M-tiles) x 112 outputs (7 N-tiles), K=576 in 18 steps.
// mask layout: [pixel][sp][25]
__global__ __launch_bounds__(64) void conv3x3_mfma(const unsigned short* __restrict__ comp,
                                                   const unsigned short* __restrict__ Bp,
                                                   const float* __restrict__ b_enc,
                                                   const float* __restrict__ zp,
                                                   float* __restrict__ mask) {
    int l   = threadIdx.x;
    int c16 = l & 15;
    int lq  = l >> 4;
    int P0  = blockIdx.x * 32;
    int nimg = P0 >> 12;
    int h    = (P0 & 4095) >> 6;
    int w0   = P0 & 63;          // 0 or 32

    const char* cbase = (const char*)(comp + (size_t)nimg * 4096 * 64);
    const char* zpb   = (const char*)zp;
    int koff = lq * 16;          // (lq*8 bf16)*2B

    f32x4 acc[2][7];
#pragma unroll
    for (int mt = 0; mt < 2; mt++)
#pragma unroll
        for (int nt = 0; nt < 7; nt++) acc[mt][nt] = f32x4{0.f, 0.f, 0.f, 0.f};

    const char* bbase = (const char*)Bp + (lq * 112 + c16) * 16;

    int wf0 = w0 + c16;       // mt=0 pixel w
    int wf1 = wf0 + 16;       // mt=1 pixel w

#pragma unroll
    for (int tap = 0; tap < 9; tap++) {
        int dy = tap / 3 - 1, dx = tap % 3 - 1;
        int hh = h + dy;
        bool vy = (unsigned)hh < 64u;
        int ww0 = wf0 + dx, ww1 = wf1 + dx;
        const char* ap0 = (vy && (unsigned)ww0 < 64u) ? cbase + (hh * 64 + ww0) * 128 : zpb;
        const char* ap1 = (vy && (unsigned)ww1 < 64u) ? cbase + (hh * 64 + ww1) * 128 : zpb;
#pragma unroll
        for (int half = 0; half < 2; half++) {
            int s = tap * 2 + half;
            bf16x8 a0 = *(const bf16x8*)(ap0 + koff + half * 64);
            bf16x8 a1 = *(const bf16x8*)(ap1 + koff + half * 64);
            const char* bptr = bbase + s * 7168;
            bf16x8 bf[7];
#pragma unroll
            for (int nt = 0; nt < 7; nt++) bf[nt] = *(const bf16x8*)(bptr + nt * 256);
#pragma unroll
            for (int nt = 0; nt < 7; nt++) {
                acc[0][nt] = __builtin_amdgcn_mfma_f32_16x16x32_bf16(a0, bf[nt], acc[0][nt], 0, 0, 0);
                acc[1][nt] = __builtin_amdgcn_mfma_f32_16x16x32_bf16(a1, bf[nt], acc[1][nt], 0, 0, 0);
            }
        }
    }

    // bias + fused softmax.  n = nt*16+c16 = 4j+sp; sp=c16&3, j=nt*4+(c16>>2).
    // group (pixel,sp) spans lanes c16^{4,8,12} -> shfl_xor 4,8.
    float bias[7];
#pragma unroll
    for (int nt = 0; nt < 7; nt++) {
        int n = nt * 16 + c16;
        bias[nt] = (n < 100) ? b_enc[n] : 0.f;
    }
    int nvalid = (c16 < 4) ? 7 : 6;

#pragma unroll
    for (int mt = 0; mt < 2; mt++) {
#pragma unroll
        for (int r = 0; r < 4; r++) {
            float v[7];
#pragma unroll
            for (int nt = 0; nt < 7; nt++) v[nt] = acc[mt][nt][r] + bias[nt];
            float m = v[0];
#pragma unroll
            for (int nt = 1; nt < 7; nt++) if (nt < nvalid) m = fmaxf(m, v[nt]);
            m = fmaxf(m, __shfl_xor(m, 4));
            m = fmaxf(m, __shfl_xor(m, 8));
            float e[7];
            float s = 0.f;
#pragma unroll
            for (int nt = 0; nt < 7; nt++) {
                e[nt] = (nt < nvalid) ? __expf(v[nt] - m) : 0.f;
                s += e[nt];
            }
            s += __shfl_xor(s, 4);
            s += __shfl_xor(s, 8);
            float inv = 1.f / s;
            int pixel = P0 + mt * 16 + lq * 4 + r;
            float* mp = mask + (size_t)pixel * 100 + (c16 & 3) * 25 + (c16 >> 2);
#pragma unroll
            for (int nt = 0; nt < 7; nt++) if (nt < nvalid) mp[nt * 4] = e[nt] * inv;
        }
    }
}

// ---------------- kernel 3: reassembly ----------------
__global__ __launch_bounds__(256) void reassemble(const float* __restrict__ x,
                                                  const float* __restrict__ mask,
                                                  float* __restrict__ out) {
    int w  = threadIdx.x & 63;
    int cq = threadIdx.x >> 6;   // 0..3
    int b  = blockIdx.x;
    int h  = b & 63;
    int rest = b >> 6;           // n*8 + cgb
    int cgb = rest & 7;
    int n   = rest >> 3;
    int c0  = cgb * 32 + cq * 8;

    int pixel = (n * 64 + h) * 64 + w;
    const float* mp = mask + (size_t)pixel * 100;

    float msk[100];
#pragma unroll
    for (int i = 0; i < 25; i++) {
        float4 v = reinterpret_cast<const float4*>(mp)[i];
        msk[i * 4 + 0] = v.x;
        msk[i * 4 + 1] = v.y;
        msk[i * 4 + 2] = v.z;
        msk[i * 4 + 3] = v.w;
    }

    int yy0[5], xx0[5];
    float vmy[5], vmx[5];
#pragma unroll
    for (int d = 0; d < 5; d++) {
        int y = h + d - 2;
        int xcol = w + d - 2;
        int ycl = min(max(y, 0), 63);
        int xcl = min(max(xcol, 0), 63);
        yy0[d] = ycl * 64;
        xx0[d] = xcl;
        vmy[d] = (y == ycl) ? 1.f : 0.f;
        vmx[d] = (xcol == xcl) ? 1.f : 0.f;
    }

    for (int c = c0; c < c0 + 8; c++) {
        const float* xc = x + ((size_t)(n * CI + c)) * 4096;
        float xv[25];
#pragma unroll
        for (int j = 0; j < 25; j++) {
            int dy = j / 5, dx = j % 5;
            xv[j] = xc[yy0[dy] + xx0[dx]] * (vmy[dy] * vmx[dx]);
        }
        float a0 = 0.f, a1 = 0.f, a2 = 0.f, a3 = 0.f;
#pragma unroll
        for (int j = 0; j < 25; j++) {
            a0 += msk[0 * 25 + j] * xv[j];
            a1 += msk[1 * 25 + j] * xv[j];
            a2 += msk[2 * 25 + j] * xv[j];
            a3 += msk[3 * 25 + j] * xv[j];
        }
        float* op = out + ((size_t)(n * CI + c) * 128 + 2 * h) * 128 + 2 * w;
        reinterpret_cast<float2*>(op)[0] = make_float2(a0, a1);
        reinterpret_cast<float2*>(op + 128)[0] = make_float2(a2, a3);
    }
}

extern "C" void kernel_launch(void* const* d_in, const int* in_sizes, int n_in,
                              void* d_out, int out_size, void* d_ws, size_t ws_size,
                              hipStream_t stream) {
    const float* x      = (const float*)d_in[0];
    const float* w_comp = (const float*)d_in[1];
    const float* b_comp = (const float*)d_in[2];
    const float* w_enc  = (const float*)d_in[3];
    const float* b_enc  = (const float*)d_in[4];
    float* out = (float*)d_out;

    // workspace layout (bytes)
    char* ws = (char*)d_ws;
    float*          zp   = (float*)(ws + 0);                 // 256 B zeros
    float*          wT1  = (float*)(ws + 256);               // 64 KB
    unsigned short* Bp   = (unsigned short*)(ws + 65792);    // 72*112*8*2 = 129024 B
    unsigned short* comp = (unsigned short*)(ws + 194816);   // 32768*64*2 = 4 MB
    float*          mask = (float*)(ws + 4389120);           // 32768*100*4 = 13.1 MB
    // total ~17.5 MB

    prep_weights<<<252, 256, 0, stream>>>(w_comp, w_enc, wT1, Bp, zp);
    conv1x1<<<512, 256, 0, stream>>>(x, wT1, b_comp, comp);
    conv3x3_mfma<<<1024, 64, 0, stream>>>(comp, Bp, b_enc, zp, mask);
    reassemble<<<4096, 256, 0, stream>>>(x, mask, out);
}